// Round 1
// 325.030 us; speedup vs baseline: 1.0079x; 1.0079x over previous
//
#include <hip/hip_runtime.h>

// Correlation1D on MI355X (gfx950), round 5.
// out[b,d,h,w] = (1/256) * sum_c in1[b,c,h,w] * in2[b,c,h,w+d-40]
// B=8 C=256 H=96 W=192 D=81 PAD=40.
//
// R5: latency-bound fix (R4: MfmaUtil 2.2%, VALUBusy 15%, HBM 1.57 TB/s, all
// idle -> waiting on the per-chunk vmcnt(0) drain at __syncthreads).
// KC=16 ping-pong LDS buffers (same 49,664 B total -> still 3 blocks/CU),
// raw s_barrier + counted s_waitcnt vmcnt(24): chunk m+1's 24 async
// global_load_lds stay in flight across the barrier while chunk m computes
// (T3/T4 counted-vmcnt pattern from the 8-phase GEMM template).
// MFMA: 16x16x16 bf16 (K=16). Fragment k = 4*lq+t (K-halved version of the
// verified 16x16x32 mapping); C/D layout identical -> band + epilogue reused.

typedef __attribute__((ext_vector_type(8))) short short8;     // 8 bf16
typedef __attribute__((ext_vector_type(4))) short short4v;    // 4 bf16
typedef __attribute__((ext_vector_type(4))) float float4v;

#if defined(__has_builtin)
#if __has_builtin(__builtin_amdgcn_mfma_f32_16x16x16bf16_1k)
#define HAVE_MFMA16 1
#endif
#endif
#ifndef HAVE_MFMA16
#define HAVE_MFMA16 0
#endif

__device__ __forceinline__ unsigned short f2bf(float f) {
  // round-to-nearest-even fp32 -> bf16
  unsigned int u = __float_as_uint(f);
  return (unsigned short)((u + 0x7FFFu + ((u >> 16) & 1u)) >> 16);
}

__device__ __forceinline__ void glds4(const float* g, float* l) {
  __builtin_amdgcn_global_load_lds(
      (const __attribute__((address_space(1))) void*)g,
      (__attribute__((address_space(3))) void*)l, 4, 0, 0);
}

__global__ __launch_bounds__(256, 3) void corr1d_kernel(
    const float* __restrict__ in1, const float* __restrict__ in2,
    float* __restrict__ out) {
  constexpr int W = 192, H = 96, C = 256, D = 81;
  constexpr int HW = H * W;          // c-stride in elements
  constexpr int KC = 16;             // channels per chunk (16 chunks)
  constexpr int SR = 194;            // LDS row stride (floats): 2-way = free
  constexpr int ES = 196;            // epilogue row stride (16B-aligned rows)
  constexpr int BUF = KC * SR;       // floats per array per buffer (3104)

  // LDS: 2 ping-pong buffers x (A[16][194] + B[16][194]) fp32 = 49,664 B
  // -> 3 blocks/CU. Epilogue overlays as float E[41][196] (32,144 B).
  __shared__ __align__(16) float smem[4 * BUF];
  float* E = smem;

  const int bh = blockIdx.x;
  const int b = bh / H, h = bh % H;
  const int tid = threadIdx.x;
  const int lane = tid & 63;
  const int wv = tid >> 6;           // wave 0..3, owns w-tiles 3wv..3wv+2
  const int l15 = lane & 15, lq = lane >> 4;
  const int base = (b * C * H + h) * W;

  float4v acc[3][6];
#pragma unroll
  for (int i = 0; i < 3; ++i)
#pragma unroll
    for (int jj = 0; jj < 6; ++jj) acc[i][jj] = (float4v){0.f, 0.f, 0.f, 0.f};

  // ---- stage chunk m (16 channels) into buffer p: wave wv loads rows
  // 4wv..4wv+3, 3 x 256B per input row -> 24 async direct-to-LDS loads/wave.
  auto stage = [&](int m, int p) {
    const int c0 = KC * m;
    float* As = smem + p * (2 * BUF);
    float* Bs = As + BUF;
#pragma unroll
    for (int r = 0; r < 4; ++r) {
      const int k = 4 * wv + r;
      const float* g1 = in1 + base + (c0 + k) * HW + lane;
      const float* g2 = in2 + base + (c0 + k) * HW + lane;
      float* lA = As + k * SR;
      float* lB = Bs + k * SR;
#pragma unroll
      for (int g = 0; g < 3; ++g) {
        glds4(g1 + 64 * g, lA + 64 * g);
        glds4(g2 + 64 * g, lB + 64 * g);
      }
    }
  };

  // ---- compute chunk resident in buffer p: fragments (fp32 LDS -> bf16
  // regs) + banded MFMA. 18 MFMAs per wave per chunk.
  auto compute_chunk = [&](int p) {
    const float* As = smem + p * (2 * BUF);
    const float* Bs = As + BUF;
#if HAVE_MFMA16
    short4v af[3];
#pragma unroll
    for (int i = 0; i < 3; ++i) {
      const float* ap = As + 48 * wv + 16 * i + l15;
      unsigned short o[4];
#pragma unroll
      for (int t = 0; t < 4; ++t) o[t] = f2bf(ap[(4 * lq + t) * SR]);
      af[i] = *(const short4v*)o;
    }
#pragma unroll
    for (int jt = 0; jt < 8; ++jt) {
      const int j = 16 * (3 * wv + jt) + l15;     // padded j coord
      const bool ok = (j >= 40) && (j < 232);     // in2 col = j-40
      const float* bp = Bs + (ok ? (j - 40) : 0);
      unsigned short o[4];
#pragma unroll
      for (int t = 0; t < 4; ++t) {
        float v = ok ? bp[(4 * lq + t) * SR] : 0.0f;
        o[t] = f2bf(v);
      }
      short4v bfr = *(const short4v*)o;
#pragma unroll
      for (int i = 0; i < 3; ++i) {
        const int jj = jt - i;                    // compile-time after unroll
        if (jj >= 0 && jj < 6)
          acc[i][jj] = __builtin_amdgcn_mfma_f32_16x16x16bf16_1k(
              af[i], bfr, acc[i][jj], 0, 0, 0);
      }
    }
#else
    // Fallback: zero-padded 16x16x32 (upper 16 k-lanes contribute zeros).
    const bool okq = (lq < 2);
    const int rb = okq ? 8 * lq : 0;              // in-bounds row base
    short8 af[3];
#pragma unroll
    for (int i = 0; i < 3; ++i) {
      const float* ap = As + 48 * wv + 16 * i + l15;
      unsigned short o[8];
#pragma unroll
      for (int t = 0; t < 8; ++t) {
        float v = ap[(rb + t) * SR];
        o[t] = okq ? f2bf(v) : (unsigned short)0;
      }
      af[i] = *(const short8*)o;
    }
#pragma unroll
    for (int jt = 0; jt < 8; ++jt) {
      const int j = 16 * (3 * wv + jt) + l15;
      const bool ok = (j >= 40) && (j < 232);
      const float* bp = Bs + (ok ? (j - 40) : 0);
      unsigned short o[8];
#pragma unroll
      for (int t = 0; t < 8; ++t) {
        float v = bp[(rb + t) * SR];
        o[t] = (ok && okq) ? f2bf(v) : (unsigned short)0;
      }
      short8 bfr = *(const short8*)o;
#pragma unroll
      for (int i = 0; i < 3; ++i) {
        const int jj = jt - i;
        if (jj >= 0 && jj < 6)
          acc[i][jj] = __builtin_amdgcn_mfma_f32_16x16x32_bf16(
              af[i], bfr, acc[i][jj], 0, 0, 0);
      }
    }
#endif
  };

  // ---- software-pipelined main loop: 16 chunks, ping-pong buffers.
  // Per iteration: issue next chunk's 24 loads, wait vmcnt(24) (= all of the
  // CURRENT chunk's loads done, next chunk's still in flight), raw barrier,
  // compute, raw barrier (all readers done before buffer is re-staged).
  stage(0, 0);
#pragma unroll 1
  for (int t7 = 0; t7 < 7; ++t7) {               // chunks 0..13
    stage(2 * t7 + 1, 1);
    asm volatile("s_waitcnt vmcnt(24)" ::: "memory");
    __builtin_amdgcn_s_barrier();
    compute_chunk(0);
    __builtin_amdgcn_s_barrier();
    stage(2 * t7 + 2, 0);
    asm volatile("s_waitcnt vmcnt(24)" ::: "memory");
    __builtin_amdgcn_s_barrier();
    compute_chunk(1);
    __builtin_amdgcn_s_barrier();
  }
  stage(15, 1);                                  // chunk 14
  asm volatile("s_waitcnt vmcnt(24)" ::: "memory");
  __builtin_amdgcn_s_barrier();
  compute_chunk(0);
  __builtin_amdgcn_s_barrier();
  asm volatile("s_waitcnt vmcnt(0)" ::: "memory");  // chunk 15: drain
  __builtin_amdgcn_s_barrier();
  compute_chunk(1);

  // ---- epilogue: D layout col(j)=l15, row(w)=4lq+r -> d = 16jj+l15-4lq-r.
  // Two d-phases through LDS overlay; full-row float4 coalesced stores.
  const float scale = 1.0f / 256.0f;
#pragma unroll
  for (int p = 0; p < 2; ++p) {
    const int dlo = p ? 41 : 0;
    const int nd  = p ? 40 : 41;
    __syncthreads();                 // buffers / previous E free
#pragma unroll
    for (int i = 0; i < 3; ++i)
#pragma unroll
      for (int jj = 0; jj < 6; ++jj)
#pragma unroll
        for (int r = 0; r < 4; ++r) {
          const int d = 16 * jj + l15 - 4 * lq - r;
          const int w = 48 * wv + 16 * i + 4 * lq + r;
          if (d >= dlo && d < dlo + nd)
            E[(d - dlo) * ES + w] = acc[i][jj][r] * scale;
        }
    __syncthreads();
    for (int t = tid; t < nd * 48; t += 256) {
      const int dr = t / 48, g = t % 48;
      float4v val = *(const float4v*)(E + dr * ES + 4 * g);
      *(float4v*)(out + ((b * D + dlo + dr) * H + h) * W + 4 * g) = val;
    }
  }
}

extern "C" void kernel_launch(void* const* d_in, const int* in_sizes, int n_in,
                              void* d_out, int out_size, void* d_ws, size_t ws_size,
                              hipStream_t stream) {
  const float* in1 = (const float*)d_in[0];
  const float* in2 = (const float*)d_in[1];
  float* out = (float*)d_out;
  (void)in_sizes; (void)n_in; (void)out_size; (void)d_ws; (void)ws_size;
  corr1d_kernel<<<dim3(768), dim3(256), 0, stream>>>(in1, in2, out);
}